// Round 1
// baseline (1478.282 us; speedup 1.0000x reference)
//
#include <hip/hip_runtime.h>
#include <math.h>

#define SPB 8  // samples per block: 256 threads, 32 lanes per sample

__global__ __launch_bounds__(256)
void geodesic_loss_kernel(const float* __restrict__ yhat,
                          const float* __restrict__ y,
                          float* __restrict__ out, int B)
{
    __shared__ float G1[SPB][32][32];   // \hat{G}_1 per sample slot (32 KB)
    __shared__ float bl[SPB];

    const int t      = threadIdx.x;
    const int slot   = t >> 5;    // 0..7  sample within block
    const int lane32 = t & 31;    // column index owned by this lane
    const int lane64 = t & 63;    // lane within wave (for ds_bpermute)

    int b = blockIdx.x * SPB + slot;
    const float valid = (b < B) ? 1.f : 0.f;
    if (b >= B) b = B - 1;

    const float tol2 = 1e-12f;    // (gamma/sqrt(alpha*beta))^2 threshold

    float a[32];                  // this lane's column (registers, static idx only)
    float diagAcc = 0.f;          // sum of log(lambda)^2 over owned columns
    float S = 0.f;                // sum over i of (ghat1_i . ghat2_j)^2

    for (int phase = 0; phase < 2; ++phase) {
        // symmetric matrix: column j == row j (contiguous, coalesced float4 loads)
        const float* A = (phase == 0 ? yhat : y) + ((size_t)b << 10) + (lane32 << 5);
        #pragma unroll
        for (int c = 0; c < 8; ++c) {
            float4 v = reinterpret_cast<const float4*>(A)[c];
            a[4*c+0] = v.x; a[4*c+1] = v.y; a[4*c+2] = v.z; a[4*c+3] = v.w;
        }
        float nrm = 0.f;          // cached squared norm of own column
        #pragma unroll
        for (int r = 0; r < 32; ++r) nrm = fmaf(a[r], a[r], nrm);

        // one-sided Jacobi sweeps, XOR pair ordering
        for (int sweep = 0; sweep < 12; ++sweep) {
            float viol = -1.f;
            for (int mask = 1; mask < 32; ++mask) {
                const int srcidx = ((lane64 ^ mask) << 2);
                float bcol[32];
                #pragma unroll
                for (int r = 0; r < 32; ++r)
                    bcol[r] = __int_as_float(
                        __builtin_amdgcn_ds_bpermute(srcidx, __float_as_int(a[r])));
                float nb = __int_as_float(
                    __builtin_amdgcn_ds_bpermute(srcidx, __float_as_int(nrm)));

                float gamma = 0.f;
                #pragma unroll
                for (int r = 0; r < 32; ++r) gamma = fmaf(a[r], bcol[r], gamma);

                const bool isLo = (lane32 ^ mask) > lane32;  // role: lower column idx
                float ab = nrm * nb;
                float g2 = gamma * gamma;
                viol = fmaxf(viol, g2 - tol2 * ab);
                bool dorot = g2 > tol2 * ab;
                float g  = dorot ? gamma : 1.f;
                // canonical rotation defined from the lower-index column's view:
                float zl = isLo ? nrm : nb;
                float zh = isLo ? nb  : nrm;
                float zeta = (zh - zl) / (2.f * g);
                float tt = copysignf(1.f, zeta) /
                           (fabsf(zeta) + sqrtf(fmaf(zeta, zeta, 1.f)));
                float cc = rsqrtf(fmaf(tt, tt, 1.f));
                float ss = cc * tt;
                if (!dorot) { cc = 1.f; ss = 0.f; tt = 0.f; }
                float se = isLo ? -ss : ss;   // lo: a' = c a - s b ; hi: a' = s b + c a
                float te = isLo ? -tt : tt;   // lo: n' = n - t*g   ; hi: n' = n + t*g
                #pragma unroll
                for (int r = 0; r < 32; ++r) a[r] = fmaf(se, bcol[r], cc * a[r]);
                nrm = fmaf(te, gamma, nrm);
            }
            if (__ballot(viol > 0.f) == 0ull) break;
        }

        // eigenvalue = final column norm (fresh dot kills cached-norm drift)
        float lam2 = 0.f;
        #pragma unroll
        for (int r = 0; r < 32; ++r) lam2 = fmaf(a[r], a[r], lam2);
        float ll = 0.5f * logf(lam2);          // log(lambda) >= 0 (SPD, eig >= 1)
        diagAcc = fmaf(ll, ll, diagAcc);
        float sc = sqrtf(fmaxf(ll, 0.f) / lam2);  // sqrt(log l)/l folded into column
        #pragma unroll
        for (int r = 0; r < 32; ++r) a[r] *= sc;

        if (phase == 0) {
            // store ghat1 column; float4 chunks rotated by column to cut the
            // 32-way same-bank write conflict to 4-way
            #pragma unroll
            for (int c = 0; c < 8; ++c) {
                float4 v = make_float4(a[4*c], a[4*c+1], a[4*c+2], a[4*c+3]);
                reinterpret_cast<float4*>(&G1[slot][lane32][0])[(c + lane32) & 7] = v;
            }
            // same 32 lanes (same wave) read it back in phase 1: no barrier needed
        } else {
            // S_j = sum_i (ghat1_i . ghat2_j)^2 ; broadcast b128 reads from LDS
            for (int i = 0; i < 32; ++i) {
                const float4* col = reinterpret_cast<const float4*>(&G1[slot][i][0]);
                float d0 = 0.f, d1 = 0.f;
                #pragma unroll
                for (int c = 0; c < 8; c += 2) {
                    float4 v0 = col[(c + i) & 7];
                    float4 v1 = col[(c + 1 + i) & 7];
                    d0 = fmaf(v0.x, a[4*c+0], d0); d0 = fmaf(v0.y, a[4*c+1], d0);
                    d0 = fmaf(v0.z, a[4*c+2], d0); d0 = fmaf(v0.w, a[4*c+3], d0);
                    d1 = fmaf(v1.x, a[4*c+4], d1); d1 = fmaf(v1.y, a[4*c+5], d1);
                    d1 = fmaf(v1.z, a[4*c+6], d1); d1 = fmaf(v1.w, a[4*c+7], d1);
                }
                float d = d0 + d1;
                S = fmaf(d, d, S);
            }
        }
    }

    // tr(D^2) partial per lane, reduce over the 32 lanes of this sample
    float p = fmaf(-2.f, S, diagAcc);
    #pragma unroll
    for (int m = 16; m >= 1; m >>= 1)
        p += __int_as_float(
            __builtin_amdgcn_ds_bpermute(((lane64 ^ m) << 2), __float_as_int(p)));
    if (lane32 == 0) bl[slot] = valid * sqrtf(fmaxf(p, 0.f));
    __syncthreads();
    if (t == 0) {
        float sum = 0.f;
        #pragma unroll
        for (int i = 0; i < SPB; ++i) sum += bl[i];
        atomicAdd(out, sum);
    }
}

extern "C" void kernel_launch(void* const* d_in, const int* in_sizes, int n_in,
                              void* d_out, int out_size, void* d_ws, size_t ws_size,
                              hipStream_t stream)
{
    const float* yhat = (const float*)d_in[0];
    const float* y    = (const float*)d_in[1];
    float* out = (float*)d_out;
    const int B = in_sizes[0] / 1024;   // 32*32 per matrix

    hipMemsetAsync(out, 0, sizeof(float), stream);
    const int grid = (B + SPB - 1) / SPB;
    hipLaunchKernelGGL(geodesic_loss_kernel, dim3(grid), dim3(256), 0, stream,
                       yhat, y, out, B);
}

// Round 2
// 1277.199 us; speedup vs baseline: 1.1574x; 1.1574x over previous
//
#include <hip/hip_runtime.h>
#include <math.h>

#define SPB 8           // samples per block: 256 threads, 32 lanes per sample
#define TOL2 1e-8f      // (gamma^2)/(alpha*beta) threshold, tau = 1e-4

__device__ __forceinline__ float bperm(int srcidx, float x) {
    return __int_as_float(__builtin_amdgcn_ds_bpermute(srcidx, __float_as_int(x)));
}

template <int CTRL>
__device__ __forceinline__ float dppx(float x) {
    // quad_perm DPP: XOR-1 = 0xB1, XOR-2 = 0x4E, XOR-3 = 0x1B (VALU pipe, no DS)
    return __int_as_float(__builtin_amdgcn_mov_dpp(__float_as_int(x), CTRL, 0xF, 0xF, true));
}

// One Jacobi rotation step given the partner column materialized in registers.
// Both lanes of a pair compute identical (c,s) via the lower-index-canonical form.
__device__ __forceinline__ void jstep(float (&a)[32], float& nrm,
                                      const float (&b)[32], float nb,
                                      bool isLo, float& viol)
{
    float gamma = 0.f;
    #pragma unroll
    for (int r = 0; r < 32; ++r) gamma = fmaf(a[r], b[r], gamma);

    float ab = nrm * nb;
    float g2 = gamma * gamma;
    viol = fmaxf(viol, g2 - TOL2 * ab);
    bool dorot = g2 > TOL2 * ab;
    float g = dorot ? gamma : 1.f;
    float zl = isLo ? nrm : nb;
    float zh = isLo ? nb  : nrm;
    float zeta = (zh - zl) / (2.f * g);
    float tt = copysignf(1.f, zeta) /
               (fabsf(zeta) + sqrtf(fmaf(zeta, zeta, 1.f)));
    float cc = rsqrtf(fmaf(tt, tt, 1.f));
    float ss = cc * tt;
    if (!dorot) { cc = 1.f; ss = 0.f; tt = 0.f; }
    float se = isLo ? -ss : ss;   // lo: a' = c a - s b ; hi: a' = s b + c a
    float te = isLo ? -tt : tt;   // lo: n' = n - t*g   ; hi: n' = n + t*g
    #pragma unroll
    for (int r = 0; r < 32; ++r) a[r] = fmaf(se, b[r], cc * a[r]);
    nrm = fmaf(te, gamma, nrm);
}

__global__ __launch_bounds__(256, 4)
void geodesic_loss_kernel(const float* __restrict__ yhat,
                          const float* __restrict__ y,
                          float* __restrict__ out, int B)
{
    __shared__ float G1[SPB][32][32];   // \hat{G}_1 per sample slot (32 KB)
    __shared__ float bl[SPB];

    const int t      = threadIdx.x;
    const int slot   = t >> 5;    // 0..7  sample within block
    const int lane32 = t & 31;    // column index owned by this lane
    const int lane64 = t & 63;    // lane within wave (for ds_bpermute)

    int b = blockIdx.x * SPB + slot;
    const float valid = (b < B) ? 1.f : 0.f;
    if (b >= B) b = B - 1;

    float a[32];                  // this lane's column (registers, static idx only)
    float diagAcc = 0.f;          // sum of log(lambda)^2 over owned columns
    float S = 0.f;                // sum over i of (ghat1_i . ghat2_j)^2

    for (int phase = 0; phase < 2; ++phase) {
        // symmetric matrix: column j == row j (contiguous, coalesced float4 loads)
        const float* A = (phase == 0 ? yhat : y) + ((size_t)b << 10) + (lane32 << 5);
        #pragma unroll
        for (int c = 0; c < 8; ++c) {
            float4 v = reinterpret_cast<const float4*>(A)[c];
            a[4*c+0] = v.x; a[4*c+1] = v.y; a[4*c+2] = v.z; a[4*c+3] = v.w;
        }
        float nrm = 0.f;          // cached squared norm of own column
        #pragma unroll
        for (int r = 0; r < 32; ++r) nrm = fmaf(a[r], a[r], nrm);

        // one-sided Jacobi sweeps, XOR pair ordering
        for (int sweep = 0; sweep < 12; ++sweep) {
            float viol = -1.f;

            {   // mask 1 via DPP (VALU pipe)
                float bc[32], nb;
                #pragma unroll
                for (int r = 0; r < 32; ++r) bc[r] = dppx<0xB1>(a[r]);
                nb = dppx<0xB1>(nrm);
                jstep(a, nrm, bc, nb, (lane32 & 1) == 0, viol);
            }
            {   // mask 2 via DPP
                float bc[32], nb;
                #pragma unroll
                for (int r = 0; r < 32; ++r) bc[r] = dppx<0x4E>(a[r]);
                nb = dppx<0x4E>(nrm);
                jstep(a, nrm, bc, nb, (lane32 & 2) == 0, viol);
            }
            {   // mask 3 via DPP
                float bc[32], nb;
                #pragma unroll
                for (int r = 0; r < 32; ++r) bc[r] = dppx<0x1B>(a[r]);
                nb = dppx<0x1B>(nrm);
                jstep(a, nrm, bc, nb, (lane32 ^ 3) > lane32, viol);
            }
            // masks 4..31 via ds_bpermute, single materialization of bcol
            for (int mask = 4; mask < 32; ++mask) {
                const int srcidx = ((lane64 ^ mask) << 2);
                float bc[32], nb;
                #pragma unroll
                for (int r = 0; r < 32; ++r) bc[r] = bperm(srcidx, a[r]);
                nb = bperm(srcidx, nrm);
                jstep(a, nrm, bc, nb, (lane32 ^ mask) > lane32, viol);
            }

            if (__ballot(viol > 0.f) == 0ull) break;
        }

        // eigenvalue = final column norm (fresh dot kills cached-norm drift)
        float lam2 = 0.f;
        #pragma unroll
        for (int r = 0; r < 32; ++r) lam2 = fmaf(a[r], a[r], lam2);
        float ll = 0.5f * logf(lam2);          // log(lambda) >= 0 (SPD, eig >= 1)
        diagAcc = fmaf(ll, ll, diagAcc);
        float sc = sqrtf(fmaxf(ll, 0.f) / lam2);  // sqrt(log l)/l folded into column
        #pragma unroll
        for (int r = 0; r < 32; ++r) a[r] *= sc;

        if (phase == 0) {
            // store ghat1 column; float4 chunks rotated by column to cut the
            // 32-way same-bank write conflict to 4-way
            #pragma unroll
            for (int c = 0; c < 8; ++c) {
                float4 v = make_float4(a[4*c], a[4*c+1], a[4*c+2], a[4*c+3]);
                reinterpret_cast<float4*>(&G1[slot][lane32][0])[(c + lane32) & 7] = v;
            }
            // same 32 lanes (same wave) read it back in phase 1: no barrier needed
        } else {
            // S_j = sum_i (ghat1_i . ghat2_j)^2 ; broadcast b128 reads from LDS
            for (int i = 0; i < 32; ++i) {
                const float4* col = reinterpret_cast<const float4*>(&G1[slot][i][0]);
                float d0 = 0.f, d1 = 0.f;
                #pragma unroll
                for (int c = 0; c < 8; c += 2) {
                    float4 v0 = col[(c + i) & 7];
                    float4 v1 = col[(c + 1 + i) & 7];
                    d0 = fmaf(v0.x, a[4*c+0], d0); d0 = fmaf(v0.y, a[4*c+1], d0);
                    d0 = fmaf(v0.z, a[4*c+2], d0); d0 = fmaf(v0.w, a[4*c+3], d0);
                    d1 = fmaf(v1.x, a[4*c+4], d1); d1 = fmaf(v1.y, a[4*c+5], d1);
                    d1 = fmaf(v1.z, a[4*c+6], d1); d1 = fmaf(v1.w, a[4*c+7], d1);
                }
                float d = d0 + d1;
                S = fmaf(d, d, S);
            }
        }
    }

    // tr(D^2) partial per lane, reduce over the 32 lanes of this sample
    float p = fmaf(-2.f, S, diagAcc);
    #pragma unroll
    for (int m = 16; m >= 1; m >>= 1)
        p += bperm(((lane64 ^ m) << 2), p);
    if (lane32 == 0) bl[slot] = valid * sqrtf(fmaxf(p, 0.f));
    __syncthreads();
    if (t == 0) {
        float sum = 0.f;
        #pragma unroll
        for (int i = 0; i < SPB; ++i) sum += bl[i];
        atomicAdd(out, sum);
    }
}

extern "C" void kernel_launch(void* const* d_in, const int* in_sizes, int n_in,
                              void* d_out, int out_size, void* d_ws, size_t ws_size,
                              hipStream_t stream)
{
    const float* yhat = (const float*)d_in[0];
    const float* y    = (const float*)d_in[1];
    float* out = (float*)d_out;
    const int B = in_sizes[0] / 1024;   // 32*32 per matrix

    hipMemsetAsync(out, 0, sizeof(float), stream);
    const int grid = (B + SPB - 1) / SPB;
    hipLaunchKernelGGL(geodesic_loss_kernel, dim3(grid), dim3(256), 0, stream,
                       yhat, y, out, B);
}

// Round 3
// 1197.750 us; speedup vs baseline: 1.2342x; 1.0663x over previous
//
#include <hip/hip_runtime.h>
#include <math.h>

#define SPB 8           // samples per block: 256 threads, 32 lanes per sample
#define TOL2 1e-8f      // (gamma^2)/(alpha*beta) threshold, tau = 1e-4

__device__ __forceinline__ float bperm(int srcidx, float x) {
    return __int_as_float(__builtin_amdgcn_ds_bpermute(srcidx, __float_as_int(x)));
}

template <int CTRL>
__device__ __forceinline__ float dppx(float x) {
    // quad_perm XOR1=0xB1 XOR2=0x4E XOR3=0x1B; ROW_HALF_MIRROR(X7)=0x141; ROW_MIRROR(X15)=0x140
    return __int_as_float(__builtin_amdgcn_mov_dpp(__float_as_int(x), CTRL, 0xF, 0xF, true));
}

__device__ __forceinline__ float frcp(float x)  { return __builtin_amdgcn_rcpf(x); }
__device__ __forceinline__ float fsqrt(float x) { return __builtin_amdgcn_sqrtf(x); }

// Scaled Jacobi rotation: column stored as d*ahat. Update is 1 FMA/element:
// ahat' = ahat + (te*db*rd)*bhat, d' = d/rc, rd' = rd*rc  (rc = 1/cos = sqrt(1+t^2)).
// n tracks the TRUE squared norm via n' = n + te*gamma_true.
// Both lanes of a pair compute bit-identical (zeta,t): all shared terms are
// commutative products of exchanged values.
__device__ __forceinline__ void jstep(float (&a)[32], float& n, float& d, float& rd,
                                      float (&b)[32], float nb, float db,
                                      bool isLo, float& viol)
{
    // pin the fetched partner column into VGPRs: blocks bpermute rematerialization
    #pragma unroll
    for (int r = 0; r < 32; ++r) asm("" : "+v"(b[r]));

    float gh = 0.f;
    #pragma unroll
    for (int r = 0; r < 32; ++r) gh = fmaf(a[r], b[r], gh);
    float gamma = (d * db) * gh;            // true gamma (commutative, pair-symmetric)

    float ab = n * nb;
    float g2 = gamma * gamma;
    viol = fmaxf(viol, g2 - TOL2 * ab);
    bool dorot = g2 > TOL2 * ab;
    float g  = dorot ? gamma : 1.f;
    float zl = isLo ? n : nb;
    float zh = isLo ? nb : n;
    float zeta = (zh - zl) * 0.5f * frcp(g);
    float tt = copysignf(frcp(fabsf(zeta) + fsqrt(fmaf(zeta, zeta, 1.f))), zeta);
    if (!dorot) tt = 0.f;
    float rc = fsqrt(fmaf(tt, tt, 1.f));    // 1/cos
    float te = isLo ? -tt : tt;
    float m  = (te * db) * rd;
    #pragma unroll
    for (int r = 0; r < 32; ++r) a[r] = fmaf(m, b[r], a[r]);
    n  = fmaf(te, gamma, n);
    d  = d * frcp(rc);
    rd = rd * rc;
}

template <int CTRL>
__device__ __forceinline__ void step_dpp(float (&a)[32], float& n, float& d, float& rd,
                                         bool isLo, float& viol)
{
    float b[32];
    #pragma unroll
    for (int r = 0; r < 32; ++r) b[r] = dppx<CTRL>(a[r]);
    float nb = dppx<CTRL>(n);
    float db = dppx<CTRL>(d);
    jstep(a, n, d, rd, b, nb, db, isLo, viol);
}

__global__ __launch_bounds__(256, 4)
void geodesic_loss_kernel(const float* __restrict__ yhat,
                          const float* __restrict__ y,
                          float* __restrict__ out, int B)
{
    __shared__ float G1[SPB][32][32];   // \hat{G}_1 per sample slot (32 KB)
    __shared__ float bl[SPB];

    const int t      = threadIdx.x;
    const int slot   = t >> 5;    // 0..7  sample within block
    const int lane32 = t & 31;    // column index owned by this lane
    const int lane64 = t & 63;    // lane within wave (for ds_bpermute)

    int b = blockIdx.x * SPB + slot;
    const float valid = (b < B) ? 1.f : 0.f;
    if (b >= B) b = B - 1;

    float a[32];                  // scaled column ahat (true column = d*ahat)
    float diagAcc = 0.f;          // sum of log(lambda)^2 over owned columns
    float S = 0.f;                // sum over i of (ghat1_i . ghat2_j)^2

    for (int phase = 0; phase < 2; ++phase) {
        // symmetric matrix: column j == row j (contiguous, coalesced float4 loads)
        const float* A = (phase == 0 ? yhat : y) + ((size_t)b << 10) + (lane32 << 5);
        #pragma unroll
        for (int c = 0; c < 8; ++c) {
            float4 v = reinterpret_cast<const float4*>(A)[c];
            a[4*c+0] = v.x; a[4*c+1] = v.y; a[4*c+2] = v.z; a[4*c+3] = v.w;
        }
        float n = 0.f;            // true squared norm
        #pragma unroll
        for (int r = 0; r < 32; ++r) n = fmaf(a[r], a[r], n);
        float d = 1.f, rd = 1.f;  // column scale and its reciprocal

        // one-sided Jacobi sweeps, XOR pair ordering
        for (int sweep = 0; sweep < 12; ++sweep) {
            float viol = -1.f;

            // masks {1,2,3,7,15} on the VALU pipe (DPP), rest on DS (bpermute)
            step_dpp<0xB1>(a, n, d, rd, (lane32 & 1) == 0, viol);
            step_dpp<0x4E>(a, n, d, rd, (lane32 & 2) == 0, viol);
            step_dpp<0x1B>(a, n, d, rd, (lane32 ^ 3)  > lane32, viol);
            step_dpp<0x141>(a, n, d, rd, (lane32 ^ 7)  > lane32, viol);
            step_dpp<0x140>(a, n, d, rd, (lane32 ^ 15) > lane32, viol);

            for (int mask = 4; mask < 32; ++mask) {
                if (mask == 7 || mask == 15) continue;
                const int srcidx = ((lane64 ^ mask) << 2);
                float bc[32];
                #pragma unroll
                for (int r = 0; r < 32; ++r) bc[r] = bperm(srcidx, a[r]);
                float nb = bperm(srcidx, n);
                float db = bperm(srcidx, d);
                jstep(a, n, d, rd, bc, nb, db, (lane32 ^ mask) > lane32, viol);
            }

            // fold scale back into the column (keeps d away from underflow,
            // and leaves a = true column when we exit)
            #pragma unroll
            for (int r = 0; r < 32; ++r) a[r] *= d;
            d = 1.f; rd = 1.f;

            if (__ballot(viol > 0.f) == 0ull) break;
        }

        // eigenvalue = final column norm (fresh dot kills recurrence drift)
        float lam2 = 0.f;
        #pragma unroll
        for (int r = 0; r < 32; ++r) lam2 = fmaf(a[r], a[r], lam2);
        float ll = 0.5f * logf(lam2);          // log(lambda) >= 0 (SPD, eig >= 1)
        diagAcc = fmaf(ll, ll, diagAcc);
        float sc = sqrtf(fmaxf(ll, 0.f) / lam2);  // sqrt(log l)/l folded into column
        #pragma unroll
        for (int r = 0; r < 32; ++r) a[r] *= sc;

        if (phase == 0) {
            // store ghat1 column; float4 chunks rotated by column to cut the
            // 32-way same-bank write conflict (measured 0 conflicts)
            #pragma unroll
            for (int c = 0; c < 8; ++c) {
                float4 v = make_float4(a[4*c], a[4*c+1], a[4*c+2], a[4*c+3]);
                reinterpret_cast<float4*>(&G1[slot][lane32][0])[(c + lane32) & 7] = v;
            }
            // same 32 lanes (same wave) read it back in phase 1: no barrier needed
        } else {
            // S_j = sum_i (ghat1_i . ghat2_j)^2 ; broadcast b128 reads from LDS
            for (int i = 0; i < 32; ++i) {
                const float4* col = reinterpret_cast<const float4*>(&G1[slot][i][0]);
                float d0 = 0.f, d1 = 0.f;
                #pragma unroll
                for (int c = 0; c < 8; c += 2) {
                    float4 v0 = col[(c + i) & 7];
                    float4 v1 = col[(c + 1 + i) & 7];
                    d0 = fmaf(v0.x, a[4*c+0], d0); d0 = fmaf(v0.y, a[4*c+1], d0);
                    d0 = fmaf(v0.z, a[4*c+2], d0); d0 = fmaf(v0.w, a[4*c+3], d0);
                    d1 = fmaf(v1.x, a[4*c+4], d1); d1 = fmaf(v1.y, a[4*c+5], d1);
                    d1 = fmaf(v1.z, a[4*c+6], d1); d1 = fmaf(v1.w, a[4*c+7], d1);
                }
                float dd = d0 + d1;
                S = fmaf(dd, dd, S);
            }
        }
    }

    // tr(D^2) partial per lane, reduce over the 32 lanes of this sample
    float p = fmaf(-2.f, S, diagAcc);
    #pragma unroll
    for (int m = 16; m >= 1; m >>= 1)
        p += bperm(((lane64 ^ m) << 2), p);
    if (lane32 == 0) bl[slot] = valid * sqrtf(fmaxf(p, 0.f));
    __syncthreads();
    if (t == 0) {
        float sum = 0.f;
        #pragma unroll
        for (int i = 0; i < SPB; ++i) sum += bl[i];
        atomicAdd(out, sum);
    }
}

extern "C" void kernel_launch(void* const* d_in, const int* in_sizes, int n_in,
                              void* d_out, int out_size, void* d_ws, size_t ws_size,
                              hipStream_t stream)
{
    const float* yhat = (const float*)d_in[0];
    const float* y    = (const float*)d_in[1];
    float* out = (float*)d_out;
    const int B = in_sizes[0] / 1024;   // 32*32 per matrix

    hipMemsetAsync(out, 0, sizeof(float), stream);
    const int grid = (B + SPB - 1) / SPB;
    hipLaunchKernelGGL(geodesic_loss_kernel, dim3(grid), dim3(256), 0, stream,
                       yhat, y, out, B);
}

// Round 4
// 671.109 us; speedup vs baseline: 2.2027x; 1.7847x over previous
//
#include <hip/hip_runtime.h>
#include <hip/hip_fp16.h>
#include <math.h>

#define SPB 8           // samples per block: 256 threads, 32 lanes per sample
#define TOL2 1e-6f      // (gamma^2)/(alpha*beta) threshold, tau = 1e-3

__device__ __forceinline__ float bperm(int srcidx, float x) {
    return __int_as_float(__builtin_amdgcn_ds_bpermute(srcidx, __float_as_int(x)));
}
template <int CTRL>
__device__ __forceinline__ float dppx(float x) {
    return __int_as_float(__builtin_amdgcn_mov_dpp(__float_as_int(x), CTRL, 0xF, 0xF, true));
}
template <int MASK>
__device__ __forceinline__ float swz(float x) {   // XOR swizzle within 32-lane groups
    return __int_as_float(__builtin_amdgcn_ds_swizzle(__float_as_int(x), (MASK << 10) | 0x1F));
}
__device__ __forceinline__ float frcp(float x)  { return __builtin_amdgcn_rcpf(x); }
__device__ __forceinline__ float fsqrt(float x) { return __builtin_amdgcn_sqrtf(x); }

// DPP ctrl codes: quad_perm XOR1=0xB1 XOR2=0x4E XOR3=0x1B,
// ROW_HALF_MIRROR(X7)=0x141, ROW_ROR:8(X8)=0x128, ROW_MIRROR(X15)=0x140
#define DPP_X1 0xB1
#define DPP_X2 0x4E
#define DPP_X3 0x1B
#define DPP_X7 0x141
#define DPP_X8 0x128
#define DPP_X15 0x140

// Scaled Jacobi rotation: column stored as d*ahat; update 1 FMA/element.
// Both lanes of a pair compute bit-identical params (commutative products only).
__device__ __forceinline__ void jstep(float (&a)[32], float& n, float& d, float& rd,
                                      float (&b)[32], float nb, float db,
                                      bool isLo, float& viol)
{
    // pin partner column in VGPRs (blocks rematerialization of the fetch)
    #pragma unroll
    for (int r = 0; r < 32; ++r) asm("" : "+v"(b[r]));

    // 4-way tree dot: chain latency ~40cyc instead of 128
    float g0 = 0.f, g1 = 0.f, g2 = 0.f, g3 = 0.f;
    #pragma unroll
    for (int r = 0; r < 8; ++r) {
        g0 = fmaf(a[4*r+0], b[4*r+0], g0);
        g1 = fmaf(a[4*r+1], b[4*r+1], g1);
        g2 = fmaf(a[4*r+2], b[4*r+2], g2);
        g3 = fmaf(a[4*r+3], b[4*r+3], g3);
    }
    float gh = (g0 + g1) + (g2 + g3);
    float gamma = (d * db) * gh;            // true gamma (pair-symmetric)

    float ab = n * nb;
    float g2s = gamma * gamma;
    viol = fmaxf(viol, g2s - TOL2 * ab);
    bool dorot = g2s > TOL2 * ab;
    float g  = dorot ? gamma : 1.f;
    float zl = isLo ? n : nb;
    float zh = isLo ? nb : n;
    float zeta = (zh - zl) * 0.5f * frcp(g);
    float tt = copysignf(frcp(fabsf(zeta) + fsqrt(fmaf(zeta, zeta, 1.f))), zeta);
    if (!dorot) tt = 0.f;
    float rc = fsqrt(fmaf(tt, tt, 1.f));    // 1/cos
    float te = isLo ? -tt : tt;
    float m  = (te * db) * rd;
    #pragma unroll
    for (int r = 0; r < 32; ++r) a[r] = fmaf(m, b[r], a[r]);
    n  = fmaf(te, gamma, n);
    d  = d * frcp(rc);
    rd = rd * rc;
}

template <int CTRL>
__device__ __forceinline__ void step_dpp(float (&a)[32], float& n, float& d, float& rd,
                                         bool isLo, float& viol)
{
    float b[32];
    #pragma unroll
    for (int r = 0; r < 32; ++r) b[r] = dppx<CTRL>(a[r]);
    float nb = dppx<CTRL>(n);
    float db = dppx<CTRL>(d);
    jstep(a, n, d, rd, b, nb, db, isLo, viol);
}
template <int C1, int C2>
__device__ __forceinline__ void step_dpp2(float (&a)[32], float& n, float& d, float& rd,
                                          bool isLo, float& viol)
{
    float b[32];
    #pragma unroll
    for (int r = 0; r < 32; ++r) b[r] = dppx<C2>(dppx<C1>(a[r]));
    float nb = dppx<C2>(dppx<C1>(n));
    float db = dppx<C2>(dppx<C1>(d));
    jstep(a, n, d, rd, b, nb, db, isLo, viol);
}
template <int MASK>
__device__ __forceinline__ void step_swz(float (&a)[32], float& n, float& d, float& rd,
                                         bool isLo, float& viol)
{
    float b[32];
    #pragma unroll
    for (int r = 0; r < 32; ++r) b[r] = swz<MASK>(a[r]);
    float nb = swz<MASK>(n);
    float db = swz<MASK>(d);
    jstep(a, n, d, rd, b, nb, db, isLo, viol);
}

__device__ __forceinline__ float2 up2(unsigned int w) {
    __half2 h = *reinterpret_cast<__half2*>(&w);
    return __half22float2(h);
}

__global__ __launch_bounds__(256, 2)
void geodesic_loss_kernel(const float* __restrict__ yhat,
                          const float* __restrict__ y,
                          float* __restrict__ out, int B)
{
    __shared__ unsigned short G1[SPB][32][32];   // f16 ghat1 (16 KB)
    __shared__ float bl[SPB];

    const int t      = threadIdx.x;
    const int slot   = t >> 5;
    const int lane32 = t & 31;
    const int lane64 = t & 63;

    int b = blockIdx.x * SPB + slot;
    const float valid = (b < B) ? 1.f : 0.f;
    if (b >= B) b = B - 1;

    float a[32];
    float diagAcc = 0.f;
    float S = 0.f;

    #pragma unroll 1
    for (int phase = 0; phase < 2; ++phase) {
        const float* A = (phase == 0 ? yhat : y) + ((size_t)b << 10) + (lane32 << 5);
        #pragma unroll
        for (int c = 0; c < 8; ++c) {
            float4 v = reinterpret_cast<const float4*>(A)[c];
            a[4*c+0] = v.x; a[4*c+1] = v.y; a[4*c+2] = v.z; a[4*c+3] = v.w;
        }
        float n0 = 0.f, n1 = 0.f, n2 = 0.f, n3 = 0.f;
        #pragma unroll
        for (int r = 0; r < 8; ++r) {
            n0 = fmaf(a[4*r+0], a[4*r+0], n0);
            n1 = fmaf(a[4*r+1], a[4*r+1], n1);
            n2 = fmaf(a[4*r+2], a[4*r+2], n2);
            n3 = fmaf(a[4*r+3], a[4*r+3], n3);
        }
        float n = (n0 + n1) + (n2 + n3);
        float d = 1.f, rd = 1.f;

        #pragma unroll 1
        for (int sweep = 0; sweep < 10; ++sweep) {
            float viol = -1.f;

            // masks 1..15: VALU pipe (DPP); isLo = (lane & msb(mask)) == 0
            step_dpp<DPP_X1>(a, n, d, rd, (lane32 & 1) == 0, viol);
            step_dpp<DPP_X2>(a, n, d, rd, (lane32 & 2) == 0, viol);
            step_dpp<DPP_X3>(a, n, d, rd, (lane32 & 2) == 0, viol);
            step_dpp2<DPP_X7, DPP_X3>(a, n, d, rd, (lane32 & 4) == 0, viol);  // 4
            step_dpp2<DPP_X7, DPP_X2>(a, n, d, rd, (lane32 & 4) == 0, viol);  // 5
            step_dpp2<DPP_X7, DPP_X1>(a, n, d, rd, (lane32 & 4) == 0, viol);  // 6
            step_dpp<DPP_X7>(a, n, d, rd, (lane32 & 4) == 0, viol);           // 7
            step_dpp<DPP_X8>(a, n, d, rd, (lane32 & 8) == 0, viol);           // 8
            step_dpp2<DPP_X8, DPP_X1>(a, n, d, rd, (lane32 & 8) == 0, viol);  // 9
            step_dpp2<DPP_X8, DPP_X2>(a, n, d, rd, (lane32 & 8) == 0, viol);  // 10
            step_dpp2<DPP_X8, DPP_X3>(a, n, d, rd, (lane32 & 8) == 0, viol);  // 11
            step_dpp2<DPP_X15, DPP_X3>(a, n, d, rd, (lane32 & 8) == 0, viol); // 12
            step_dpp2<DPP_X15, DPP_X2>(a, n, d, rd, (lane32 & 8) == 0, viol); // 13
            step_dpp2<DPP_X15, DPP_X1>(a, n, d, rd, (lane32 & 8) == 0, viol); // 14
            step_dpp<DPP_X15>(a, n, d, rd, (lane32 & 8) == 0, viol);          // 15
            // masks 16..31: DS pipe (ds_swizzle, XOR within 32-lane group)
            step_swz<16>(a, n, d, rd, (lane32 & 16) == 0, viol);
            step_swz<17>(a, n, d, rd, (lane32 & 16) == 0, viol);
            step_swz<18>(a, n, d, rd, (lane32 & 16) == 0, viol);
            step_swz<19>(a, n, d, rd, (lane32 & 16) == 0, viol);
            step_swz<20>(a, n, d, rd, (lane32 & 16) == 0, viol);
            step_swz<21>(a, n, d, rd, (lane32 & 16) == 0, viol);
            step_swz<22>(a, n, d, rd, (lane32 & 16) == 0, viol);
            step_swz<23>(a, n, d, rd, (lane32 & 16) == 0, viol);
            step_swz<24>(a, n, d, rd, (lane32 & 16) == 0, viol);
            step_swz<25>(a, n, d, rd, (lane32 & 16) == 0, viol);
            step_swz<26>(a, n, d, rd, (lane32 & 16) == 0, viol);
            step_swz<27>(a, n, d, rd, (lane32 & 16) == 0, viol);
            step_swz<28>(a, n, d, rd, (lane32 & 16) == 0, viol);
            step_swz<29>(a, n, d, rd, (lane32 & 16) == 0, viol);
            step_swz<30>(a, n, d, rd, (lane32 & 16) == 0, viol);
            step_swz<31>(a, n, d, rd, (lane32 & 16) == 0, viol);

            // fold scale back into column (avoids drift/underflow of d)
            #pragma unroll
            for (int r = 0; r < 32; ++r) a[r] *= d;
            d = 1.f; rd = 1.f;

            if (__ballot(viol > 0.f) == 0ull) break;
        }

        // eigenvalue = fresh final column norm
        float l0 = 0.f, l1 = 0.f, l2 = 0.f, l3 = 0.f;
        #pragma unroll
        for (int r = 0; r < 8; ++r) {
            l0 = fmaf(a[4*r+0], a[4*r+0], l0);
            l1 = fmaf(a[4*r+1], a[4*r+1], l1);
            l2 = fmaf(a[4*r+2], a[4*r+2], l2);
            l3 = fmaf(a[4*r+3], a[4*r+3], l3);
        }
        float lam2 = (l0 + l1) + (l2 + l3);
        float ll = 0.5f * logf(lam2);             // >= 0 (SPD, eig >= 1)
        diagAcc = fmaf(ll, ll, diagAcc);
        float sc = sqrtf(fmaxf(ll, 0.f) / lam2);  // sqrt(log l)/l folded in
        #pragma unroll
        for (int r = 0; r < 32; ++r) a[r] *= sc;

        if (phase == 0) {
            // pack scaled column to f16, store as 4x uint4 (own row, same wave
            // reads it back in phase 1 -> no barrier needed)
            unsigned int hw[16];
            #pragma unroll
            for (int k = 0; k < 16; ++k) {
                unsigned int lo = __half_as_ushort(__float2half(a[2*k+0]));
                unsigned int hi = __half_as_ushort(__float2half(a[2*k+1]));
                hw[k] = lo | (hi << 16);
            }
            uint4* rp = reinterpret_cast<uint4*>(&G1[slot][lane32][0]);
            #pragma unroll
            for (int c = 0; c < 4; ++c)
                rp[c] = make_uint4(hw[4*c+0], hw[4*c+1], hw[4*c+2], hw[4*c+3]);
        } else {
            // S_j = sum_i (ghat1_i . ghat2_j)^2 ; broadcast reads (conflict-free)
            for (int i = 0; i < 32; ++i) {
                const uint4* colp = reinterpret_cast<const uint4*>(&G1[slot][i][0]);
                float d0 = 0.f, d1 = 0.f;
                #pragma unroll
                for (int c = 0; c < 4; ++c) {
                    uint4 w = colp[c];
                    float2 f0 = up2(w.x), f1 = up2(w.y), f2 = up2(w.z), f3 = up2(w.w);
                    d0 = fmaf(f0.x, a[8*c+0], d0); d0 = fmaf(f0.y, a[8*c+1], d0);
                    d1 = fmaf(f1.x, a[8*c+2], d1); d1 = fmaf(f1.y, a[8*c+3], d1);
                    d0 = fmaf(f2.x, a[8*c+4], d0); d0 = fmaf(f2.y, a[8*c+5], d0);
                    d1 = fmaf(f3.x, a[8*c+6], d1); d1 = fmaf(f3.y, a[8*c+7], d1);
                }
                float dd = d0 + d1;
                S = fmaf(dd, dd, S);
            }
        }
    }

    // tr(D^2) partial per lane, reduce over the 32 lanes of this sample
    float p = fmaf(-2.f, S, diagAcc);
    #pragma unroll
    for (int m = 16; m >= 1; m >>= 1)
        p += bperm(((lane64 ^ m) << 2), p);
    if (lane32 == 0) bl[slot] = valid * sqrtf(fmaxf(p, 0.f));
    __syncthreads();
    if (t == 0) {
        float sum = 0.f;
        #pragma unroll
        for (int i = 0; i < SPB; ++i) sum += bl[i];
        atomicAdd(out, sum);
    }
}

extern "C" void kernel_launch(void* const* d_in, const int* in_sizes, int n_in,
                              void* d_out, int out_size, void* d_ws, size_t ws_size,
                              hipStream_t stream)
{
    const float* yhat = (const float*)d_in[0];
    const float* y    = (const float*)d_in[1];
    float* out = (float*)d_out;
    const int B = in_sizes[0] / 1024;   // 32*32 per matrix

    hipMemsetAsync(out, 0, sizeof(float), stream);
    const int grid = (B + SPB - 1) / SPB;
    hipLaunchKernelGGL(geodesic_loss_kernel, dim3(grid), dim3(256), 0, stream,
                       yhat, y, out, B);
}

// Round 5
// 654.030 us; speedup vs baseline: 2.2603x; 1.0261x over previous
//
#include <hip/hip_runtime.h>
#include <hip/hip_fp16.h>
#include <math.h>

#define SPB 8           // samples per block: 256 threads, 32 lanes per sample
#define TOL2 1e-6f      // (gamma^2)/(alpha*beta) threshold, tau = 1e-3

typedef float v2f __attribute__((ext_vector_type(2)));

__device__ __forceinline__ float bperm(int srcidx, float x) {
    return __int_as_float(__builtin_amdgcn_ds_bpermute(srcidx, __float_as_int(x)));
}
template <int CTRL>
__device__ __forceinline__ float dppx(float x) {
    return __int_as_float(__builtin_amdgcn_mov_dpp(__float_as_int(x), CTRL, 0xF, 0xF, true));
}
template <int MASK>
__device__ __forceinline__ float swzf(float x) {   // XOR swizzle within 32-lane groups
    return __int_as_float(__builtin_amdgcn_ds_swizzle(__float_as_int(x), (MASK << 10) | 0x1F));
}
__device__ __forceinline__ float frcp(float x)  { return __builtin_amdgcn_rcpf(x); }
__device__ __forceinline__ float fsq(float x)   { return __builtin_amdgcn_sqrtf(x); }
__device__ __forceinline__ float frsq(float x)  { return __builtin_amdgcn_rsqf(x); }

// DPP ctrl: quad_perm XOR1=0xB1 XOR2=0x4E XOR3=0x1B,
// ROW_HALF_MIRROR(X7)=0x141, ROW_ROR:8(X8)=0x128, ROW_MIRROR(X15)=0x140
#define DPP_X1 0xB1
#define DPP_X2 0x4E
#define DPP_X3 0x1B
#define DPP_X7 0x141
#define DPP_X8 0x128
#define DPP_X15 0x140

// Scaled Jacobi rotation, packed-f32 inner loops. Column stored as d*ahat in
// 16 VGPR pairs; update is 16 v_pk_fma. Both lanes of a pair derive
// bit-identical rotation params (only commutative/antisymmetric shared terms).
__device__ __forceinline__ void jstep(v2f (&a)[16], float& n, float& d, float& rd,
                                      v2f (&b)[16], float nb, float db,
                                      float hw, unsigned sgn, bool& anyrot)
{
    // pin partner column (blocks rematerialization of the 32 fetch ops)
    #pragma unroll
    for (int k = 0; k < 16; ++k) asm("" : "+v"(b[k]));

    v2f acc0 = {0.f, 0.f}, acc1 = {0.f, 0.f};
    #pragma unroll
    for (int k = 0; k < 16; k += 2) {
        asm("v_pk_fma_f32 %0, %1, %2, %0" : "+v"(acc0) : "v"(a[k]),   "v"(b[k]));
        asm("v_pk_fma_f32 %0, %1, %2, %0" : "+v"(acc1) : "v"(a[k+1]), "v"(b[k+1]));
    }
    float gh = (acc0.x + acc0.y) + (acc1.x + acc1.y);
    float gamma = (d * db) * gh;            // true gamma (pair-symmetric)
    float ab  = n * nb;
    float g2s = gamma * gamma;
    bool dorot = g2s > TOL2 * ab;
    if (__ballot(dorot) == 0ull) return;    // wave-uniform skip (verification sweeps)
    anyrot = true;

    // w = (zh-zl)/2, identical bits on both lanes; t = sign(w)*g/(|w|+sqrt(w^2+g^2))
    float w   = (nb - n) * hw;
    float hyp = fsq(fmaf(w, w, g2s));
    float tt  = gamma * copysignf(frcp(fabsf(w) + hyp), w);
    tt = dorot ? tt : 0.f;
    float u  = fmaf(tt, tt, 1.f);           // 1/cos^2
    float te = __int_as_float(__float_as_int(tt) ^ sgn);  // lo: -t, hi: +t
    float m  = (te * db) * rd;
    v2f mm = {m, m};
    #pragma unroll
    for (int k = 0; k < 16; ++k)
        asm("v_pk_fma_f32 %0, %1, %2, %0" : "+v"(a[k]) : "v"(mm), "v"(b[k]));
    n  = fmaf(te, gamma, n);
    d  = d * frsq(u);                       // parallel rsqrt/sqrt (no serial rcp)
    rd = rd * fsq(u);
}

template <int CTRL>
__device__ __forceinline__ void step_dpp(v2f (&a)[16], float& n, float& d, float& rd,
                                         float hw, unsigned sgn, bool& anyrot)
{
    v2f b[16];
    #pragma unroll
    for (int k = 0; k < 16; ++k) { b[k].x = dppx<CTRL>(a[k].x); b[k].y = dppx<CTRL>(a[k].y); }
    float nb = dppx<CTRL>(n);
    float db = dppx<CTRL>(d);
    jstep(a, n, d, rd, b, nb, db, hw, sgn, anyrot);
}
template <int MASK>
__device__ __forceinline__ void step_swz(v2f (&a)[16], float& n, float& d, float& rd,
                                         float hw, unsigned sgn, bool& anyrot)
{
    v2f b[16];
    #pragma unroll
    for (int k = 0; k < 16; ++k) { b[k].x = swzf<MASK>(a[k].x); b[k].y = swzf<MASK>(a[k].y); }
    float nb = swzf<MASK>(n);
    float db = swzf<MASK>(d);
    jstep(a, n, d, rd, b, nb, db, hw, sgn, anyrot);
}

__device__ __forceinline__ v2f up2(unsigned int w) {
    __half2 h = *reinterpret_cast<__half2*>(&w);
    float2 f = __half22float2(h);
    v2f r; r.x = f.x; r.y = f.y;
    return r;
}

#define STEP_DPP(CTRL, BIT) do { bool lo_ = (lane32 & (BIT)) == 0; \
    step_dpp<CTRL>(a, n, d, rd, lo_ ? 0.5f : -0.5f, lo_ ? 0x80000000u : 0u, anyrot); } while (0)
#define STEP_SWZ(M, BIT) do { bool lo_ = (lane32 & (BIT)) == 0; \
    step_swz<M>(a, n, d, rd, lo_ ? 0.5f : -0.5f, lo_ ? 0x80000000u : 0u, anyrot); } while (0)

__global__ __launch_bounds__(256, 3)
void geodesic_loss_kernel(const float* __restrict__ yhat,
                          const float* __restrict__ y,
                          float* __restrict__ out, int B)
{
    __shared__ unsigned short G1[SPB][32][32];   // f16 ghat1 (16 KB)
    __shared__ float bl[SPB];

    const int t      = threadIdx.x;
    const int slot   = t >> 5;
    const int lane32 = t & 31;
    const int lane64 = t & 63;

    int b = blockIdx.x * SPB + slot;
    const float valid = (b < B) ? 1.f : 0.f;
    if (b >= B) b = B - 1;

    v2f a[16];                    // scaled column (true column = d * a)
    float diagAcc = 0.f;
    float S = 0.f;

    #pragma unroll 1
    for (int phase = 0; phase < 2; ++phase) {
        const float* A = (phase == 0 ? yhat : y) + ((size_t)b << 10) + (lane32 << 5);
        #pragma unroll
        for (int c = 0; c < 8; ++c) {
            float4 v = reinterpret_cast<const float4*>(A)[c];
            a[2*c+0].x = v.x; a[2*c+0].y = v.y;
            a[2*c+1].x = v.z; a[2*c+1].y = v.w;
        }
        v2f nacc0 = {0.f, 0.f}, nacc1 = {0.f, 0.f};
        #pragma unroll
        for (int k = 0; k < 16; k += 2) {
            asm("v_pk_fma_f32 %0, %1, %1, %0" : "+v"(nacc0) : "v"(a[k]));
            asm("v_pk_fma_f32 %0, %1, %1, %0" : "+v"(nacc1) : "v"(a[k+1]));
        }
        float n = (nacc0.x + nacc0.y) + (nacc1.x + nacc1.y);
        float d = 1.f, rd = 1.f;

        #pragma unroll 1
        for (int sweep = 0; sweep < 10; ++sweep) {
            bool anyrot = false;

            STEP_DPP(DPP_X1, 1);            // 1
            STEP_DPP(DPP_X2, 2);            // 2
            STEP_DPP(DPP_X3, 2);            // 3
            STEP_SWZ(4, 4);                 // 4
            STEP_SWZ(5, 4);                 // 5
            STEP_SWZ(6, 4);                 // 6
            STEP_DPP(DPP_X7, 4);            // 7
            STEP_DPP(DPP_X8, 8);            // 8
            STEP_SWZ(9, 8);                 // 9
            STEP_SWZ(10, 8);                // 10
            STEP_SWZ(11, 8);                // 11
            STEP_SWZ(12, 8);                // 12
            STEP_SWZ(13, 8);                // 13
            STEP_SWZ(14, 8);                // 14
            STEP_DPP(DPP_X15, 8);           // 15
            STEP_SWZ(16, 16);  STEP_SWZ(17, 16);  STEP_SWZ(18, 16);  STEP_SWZ(19, 16);
            STEP_SWZ(20, 16);  STEP_SWZ(21, 16);  STEP_SWZ(22, 16);  STEP_SWZ(23, 16);
            STEP_SWZ(24, 16);  STEP_SWZ(25, 16);  STEP_SWZ(26, 16);  STEP_SWZ(27, 16);
            STEP_SWZ(28, 16);  STEP_SWZ(29, 16);  STEP_SWZ(30, 16);  STEP_SWZ(31, 16);

            if (!anyrot) break;             // d == 1 here, nothing to fold

            v2f dd2 = {d, d};               // fold scale back into column
            #pragma unroll
            for (int k = 0; k < 16; ++k)
                asm("v_pk_mul_f32 %0, %0, %1" : "+v"(a[k]) : "v"(dd2));
            d = 1.f; rd = 1.f;
        }

        // eigenvalue = fresh final column norm
        v2f lacc0 = {0.f, 0.f}, lacc1 = {0.f, 0.f};
        #pragma unroll
        for (int k = 0; k < 16; k += 2) {
            asm("v_pk_fma_f32 %0, %1, %1, %0" : "+v"(lacc0) : "v"(a[k]));
            asm("v_pk_fma_f32 %0, %1, %1, %0" : "+v"(lacc1) : "v"(a[k+1]));
        }
        float lam2 = (lacc0.x + lacc0.y) + (lacc1.x + lacc1.y);
        float ll = 0.5f * logf(lam2);             // >= 0 (SPD, eig >= 1)
        diagAcc = fmaf(ll, ll, diagAcc);
        float sc = sqrtf(fmaxf(ll, 0.f) / lam2);  // sqrt(log l)/l folded in
        v2f sc2 = {sc, sc};
        #pragma unroll
        for (int k = 0; k < 16; ++k)
            asm("v_pk_mul_f32 %0, %0, %1" : "+v"(a[k]) : "v"(sc2));

        if (phase == 0) {
            // pack scaled column to f16, store 4x uint4 (same wave reads back
            // in phase 1 -> no barrier needed)
            unsigned int hw16[16];
            #pragma unroll
            for (int k = 0; k < 16; ++k) {
                unsigned int lo = __half_as_ushort(__float2half(a[k].x));
                unsigned int hi = __half_as_ushort(__float2half(a[k].y));
                hw16[k] = lo | (hi << 16);
            }
            uint4* rp = reinterpret_cast<uint4*>(&G1[slot][lane32][0]);
            #pragma unroll
            for (int c = 0; c < 4; ++c)
                rp[c] = make_uint4(hw16[4*c+0], hw16[4*c+1], hw16[4*c+2], hw16[4*c+3]);
        } else {
            // S_j = sum_i (ghat1_i . ghat2_j)^2 ; broadcast reads (conflict-free)
            for (int i = 0; i < 32; ++i) {
                const uint4* colp = reinterpret_cast<const uint4*>(&G1[slot][i][0]);
                v2f dacc0 = {0.f, 0.f}, dacc1 = {0.f, 0.f};
                #pragma unroll
                for (int c = 0; c < 4; ++c) {
                    uint4 wv = colp[c];
                    v2f f0 = up2(wv.x), f1 = up2(wv.y), f2 = up2(wv.z), f3 = up2(wv.w);
                    asm("v_pk_fma_f32 %0, %1, %2, %0" : "+v"(dacc0) : "v"(f0), "v"(a[4*c+0]));
                    asm("v_pk_fma_f32 %0, %1, %2, %0" : "+v"(dacc1) : "v"(f1), "v"(a[4*c+1]));
                    asm("v_pk_fma_f32 %0, %1, %2, %0" : "+v"(dacc0) : "v"(f2), "v"(a[4*c+2]));
                    asm("v_pk_fma_f32 %0, %1, %2, %0" : "+v"(dacc1) : "v"(f3), "v"(a[4*c+3]));
                }
                float dd = (dacc0.x + dacc0.y) + (dacc1.x + dacc1.y);
                S = fmaf(dd, dd, S);
            }
        }
    }

    // tr(D^2) partial per lane, reduce over the 32 lanes of this sample
    float p = fmaf(-2.f, S, diagAcc);
    #pragma unroll
    for (int m = 16; m >= 1; m >>= 1)
        p += bperm(((lane64 ^ m) << 2), p);
    if (lane32 == 0) bl[slot] = valid * sqrtf(fmaxf(p, 0.f));
    __syncthreads();
    if (t == 0) {
        float sum = 0.f;
        #pragma unroll
        for (int i = 0; i < SPB; ++i) sum += bl[i];
        atomicAdd(out, sum);
    }
}

extern "C" void kernel_launch(void* const* d_in, const int* in_sizes, int n_in,
                              void* d_out, int out_size, void* d_ws, size_t ws_size,
                              hipStream_t stream)
{
    const float* yhat = (const float*)d_in[0];
    const float* y    = (const float*)d_in[1];
    float* out = (float*)d_out;
    const int B = in_sizes[0] / 1024;   // 32*32 per matrix

    hipMemsetAsync(out, 0, sizeof(float), stream);
    const int grid = (B + SPB - 1) / SPB;
    hipLaunchKernelGGL(geodesic_loss_kernel, dim3(grid), dim3(256), 0, stream,
                       yhat, y, out, B);
}